// Round 15
// baseline (1336.274 us; speedup 1.0000x reference)
//
#include <hip/hip_runtime.h>
#include <math.h>
#include <stdint.h>

#define DIMM 512
#define SLOT_S 262144                    // single-plane slot per batch (ushorts) = 512 KiB

typedef __attribute__((ext_vector_type(8))) _Float16 half8v;
typedef __attribute__((ext_vector_type(8))) unsigned short ushort8v;
typedef __attribute__((ext_vector_type(4))) float f32x4;

__device__ __forceinline__ unsigned short f2h(float f) {
    _Float16 h = (_Float16)f;                       // v_cvt_f16_f32 (RNE)
    return __builtin_bit_cast(unsigned short, h);
}
__device__ __forceinline__ float h2f(unsigned short u) {
    return (float)__builtin_bit_cast(_Float16, u);  // v_cvt_f32_f16
}
__device__ __forceinline__ float sgn_sqrt(float tv)
{
    float r = sqrtf(fabsf(tv) + 1e-5f);
    return tv > 0.f ? r : (tv < 0.f ? -r : 0.f);
}

// ---------------------------------------------------------------------------
// fp16 NS GEMM — round-12 proven body (BK=32, 17920B LDS => 8 blocks/CU,
// raw B staging, f32 affine epilogue with A re-read) + epilogue-only modes:
//   base = 1.5*a - 0.5*kscale*acc
//   mode 0: kscale=1,  v = base                      (normal NS step)
//   mode 1: kscale=rn, v = rn*base                   (it0a: Y1 from raw A)
//   mode 2: kscale=rn, v = base                      (it0b: M1, B = raw A)
//   mode 3: kscale=1,  v = sgn_sqrt(base*sqrt(n))    (it9 + signed-sqrt)
// LDS XOR-chunk involution (r7/r9-validated); symmetric 10-tile + TP=70
// half-pass mirror (r9-validated); rolled K-loop; XCD remap. grid 640*nz.
// ---------------------------------------------------------------------------
__global__ __launch_bounds__(256) void ns_single(
    const unsigned short* __restrict__ A0, const unsigned short* __restrict__ A1,
    const unsigned short* __restrict__ Bb,
    unsigned short* __restrict__ C0, unsigned short* __restrict__ C1,
    int lda, long aslot, int ldb, long bslot, int K,
    int mode, const float* __restrict__ norm, int nz)
{
    __shared__ __align__(16) unsigned short sm[8960];  // staging 8192; mirror 128x70

    const int nwg = gridDim.x;
    const int chunk = nwg >> 3;                   // nwg % 8 == 0
    const int bid = blockIdx.x;
    const int wu = (bid & 7) * chunk + (bid >> 3);
    const int per_batch = nz * 10;
    const int bz = wu / per_batch;
    const int rr = wu - bz * per_batch;
    const int z  = rr / 10;
    const int tile = rr - z * 10;
    int ti, tj;
    if (tile < 4)      { ti = 0; tj = tile; }
    else if (tile < 7) { ti = 1; tj = tile - 3; }
    else if (tile < 9) { ti = 2; tj = tile - 5; }
    else               { ti = 3; tj = 3; }

    const unsigned short* A  = (z ? A1 : A0) + (size_t)bz * aslot;
    const unsigned short* Bp = Bb + (size_t)bz * bslot;
    unsigned short* C = (z ? C1 : C0) + (size_t)bz * SLOT_S;

    float rn = 1.0f, sq = 0.0f;
    if (mode != 0) {
        const float nv = norm[bz];
        rn = 1.0f / nv;
        sq = sqrtf(nv);
    }
    const float kscale = (mode == 1 || mode == 2) ? rn : 1.0f;

    const int m0 = ti * 128;
    const int n0 = tj * 128;

    const int t = threadIdx.x;
    const int l = t & 63;
    const int w = t >> 6;
    const int wr = w >> 1, wc = w & 1;
    const int lr = l & 15;
    const int sc = (((l >> 4) ^ ((l >> 1) & 3)) << 3);   // swizzled read chunk

    // staging: thread covers row sr, global chunks {2sh, 2sh+1}; XOR'd slots
    const int sr = t >> 1, sh = t & 1;
    const int swz = (sr >> 1) & 3;
    const int slot0 = ((((sh << 1) | 0) ^ swz) << 3);
    const int slot1 = ((((sh << 1) | 1) ^ swz) << 3);
    const int wbase = sr * 32;
    const unsigned short* pA = A  + (size_t)(m0 + sr) * lda + sh * 16;
    const unsigned short* pB = Bp + (size_t)(n0 + sr) * ldb + sh * 16;

    f32x4 acc[4][4] = {};

    ushort8v a0, a1, b0, b1;
#define LOADALL(OFF) do { \
    a0 = *(const ushort8v*)(pA + (OFF));  a1 = *(const ushort8v*)(pA + (OFF) + 8); \
    b0 = *(const ushort8v*)(pB + (OFF));  b1 = *(const ushort8v*)(pB + (OFF) + 8); \
  } while (0)

    LOADALL(0);
    const int nsteps = K >> 5;
    for (int s = 0; s < nsteps; ++s) {
        __syncthreads();
        *(ushort8v*)&sm[       wbase + slot0] = a0; *(ushort8v*)&sm[       wbase + slot1] = a1;
        *(ushort8v*)&sm[4096 + wbase + slot0] = b0; *(ushort8v*)&sm[4096 + wbase + slot1] = b1;
        __syncthreads();
        if (s + 1 < nsteps) LOADALL((s + 1) * 32);

        half8v ah[4], bh[4];
#pragma unroll
        for (int f = 0; f < 4; ++f) {
            const int ra = ((wr * 64 + f * 16 + lr) << 5) + sc;
            const int rb = ((wc * 64 + f * 16 + lr) << 5) + sc;
            ah[f] = *(const half8v*)(&sm[ra]);
            bh[f] = *(const half8v*)(&sm[4096 + rb]);
        }
#pragma unroll
        for (int fm = 0; fm < 4; ++fm)
#pragma unroll
            for (int fn = 0; fn < 4; ++fn)
                acc[fm][fn] = __builtin_amdgcn_mfma_f32_16x16x32_f16(ah[fm], bh[fn], acc[fm][fn], 0, 0, 0);
    }
#undef LOADALL

    // epilogue (f32 affine): base = 1.5a - 0.5*kscale*acc; write upper tile
    // C/D layout: col = lane&15, row = (lane>>4)*4 + reg  [m89-verified]
#pragma unroll
    for (int fm = 0; fm < 4; ++fm) {
#pragma unroll
        for (int j = 0; j < 4; ++j) {
            const int row = m0 + wr * 64 + fm * 16 + (l >> 4) * 4 + j;
            const unsigned short* arow = A + (size_t)row * lda;
            const size_t crow = (size_t)row * 512;
#pragma unroll
            for (int fn = 0; fn < 4; ++fn) {
                const int col = n0 + wc * 64 + fn * 16 + lr;
                float v = 1.5f * h2f(arow[col]) - 0.5f * kscale * acc[fm][fn][j];
                if (mode == 1) v *= rn;
                else if (mode == 3) v = sgn_sqrt(v * sq);
                acc[fm][fn][j] = v;
                C[crow + col] = f2h(v);
            }
        }
    }

    // mirrored (lower) tile: two 64-row half-pass LDS transposes (TP=70)
    if (ti != tj) {
        const int TP = 70;
        unsigned short* smT = sm;
        const int cst = wc * 64 + lr;
        const int r4  = (l >> 4) * 4;
        const int rc2 = t >> 1;
        const int chh = t & 1;
        __syncthreads();
#pragma unroll
        for (int h = 0; h < 2; ++h) {
            if (wr == h) {
#pragma unroll
                for (int fm = 0; fm < 4; ++fm) {
#pragma unroll
                    for (int fn = 0; fn < 4; ++fn) {
                        ushort4 q;
                        q.x = f2h(acc[fm][fn][0]);
                        q.y = f2h(acc[fm][fn][1]);
                        q.z = f2h(acc[fm][fn][2]);
                        q.w = f2h(acc[fm][fn][3]);
                        *(ushort4*)&smT[(cst + fn * 16) * TP + r4 + fm * 16] = q;
                    }
                }
            }
            __syncthreads();
            {
                unsigned short* dst = C + (size_t)(n0 + rc2) * 512 + m0 + h * 64 + chh * 32;
                const unsigned short* srcp = &smT[rc2 * TP + chh * 32];
#pragma unroll
                for (int k = 0; k < 8; ++k)
                    *(ushort4*)(dst + k * 4) = *(const ushort4*)(srcp + k * 4);
            }
            __syncthreads();
        }
    }
}

// ---------------------------------------------------------------------------
// Gram single-fp16 (round-12 verbatim): C = (X X^T)/784, conversion fused
// into staging; symmetric 10-tile + mirror; K=800, BK=32.
// ---------------------------------------------------------------------------
__global__ __launch_bounds__(256) void gram_single(const float* __restrict__ X,
                                                   unsigned short* __restrict__ C0,
                                                   float alpha, int K)
{
    __shared__ __align__(16) unsigned short sm[8960];

    const int nwg = gridDim.x;
    const int chunk = nwg >> 3;
    const int wu = (blockIdx.x & 7) * chunk + (blockIdx.x >> 3);
    const int bz = wu / 10, tile = wu - bz * 10;
    int ti, tj;
    if (tile < 4)      { ti = 0; tj = tile; }
    else if (tile < 7) { ti = 1; tj = tile - 3; }
    else if (tile < 9) { ti = 2; tj = tile - 5; }
    else               { ti = 3; tj = 3; }
    const int m0 = ti * 128, n0 = tj * 128;
    unsigned short* C = C0 + (size_t)bz * SLOT_S;

    const int t = threadIdx.x;
    const int l = t & 63;
    const int w = t >> 6;
    const int wr = w >> 1, wc = w & 1;
    const int lr = l & 15;
    const int sc = (((l >> 4) ^ ((l >> 1) & 3)) << 3);

    const int sr = t >> 1, sh = t & 1;
    const int swz = (sr >> 1) & 3;
    const int slot0 = ((((sh << 1) | 0) ^ swz) << 3);
    const int slot1 = ((((sh << 1) | 1) ^ swz) << 3);
    const int wbase = sr * 32;

    const float* pXa = X + ((size_t)bz * 512 + m0 + sr) * 784 + sh * 16;
    const float* pXb = X + ((size_t)bz * 512 + n0 + sr) * 784 + sh * 16;

    f32x4 acc[4][4] = {};

    float4 xa0, xa1, xa2, xa3, xb0, xb1, xb2, xb3;
    ushort8v a0, a1, b0, b1;

#define GLD(OFF) do { \
    if ((OFF) + sh * 16 < 784) { \
        xa0 = *(const float4*)(pXa + (OFF));      xa1 = *(const float4*)(pXa + (OFF) + 4); \
        xa2 = *(const float4*)(pXa + (OFF) + 8);  xa3 = *(const float4*)(pXa + (OFF) + 12); \
        xb0 = *(const float4*)(pXb + (OFF));      xb1 = *(const float4*)(pXb + (OFF) + 4); \
        xb2 = *(const float4*)(pXb + (OFF) + 8);  xb3 = *(const float4*)(pXb + (OFF) + 12); \
    } else { \
        xa0 = xa1 = xa2 = xa3 = make_float4(0.f, 0.f, 0.f, 0.f); \
        xb0 = xb1 = xb2 = xb3 = make_float4(0.f, 0.f, 0.f, 0.f); \
    } } while (0)

#define CV8(F0, F1, O) do { \
    (O)[0] = f2h((F0).x); (O)[1] = f2h((F0).y); \
    (O)[2] = f2h((F0).z); (O)[3] = f2h((F0).w); \
    (O)[4] = f2h((F1).x); (O)[5] = f2h((F1).y); \
    (O)[6] = f2h((F1).z); (O)[7] = f2h((F1).w); \
  } while (0)

#define CONVALL() do { \
    CV8(xa0, xa1, a0); CV8(xa2, xa3, a1); \
    CV8(xb0, xb1, b0); CV8(xb2, xb3, b1); \
  } while (0)

    GLD(0);
    CONVALL();
    const int nsteps = K >> 5;
    for (int s = 0; s < nsteps; ++s) {
        __syncthreads();
        *(ushort8v*)&sm[       wbase + slot0] = a0; *(ushort8v*)&sm[       wbase + slot1] = a1;
        *(ushort8v*)&sm[4096 + wbase + slot0] = b0; *(ushort8v*)&sm[4096 + wbase + slot1] = b1;
        __syncthreads();
        if (s + 1 < nsteps) GLD((s + 1) * 32);

        half8v ah[4], bh[4];
#pragma unroll
        for (int f = 0; f < 4; ++f) {
            const int ra = ((wr * 64 + f * 16 + lr) << 5) + sc;
            const int rb = ((wc * 64 + f * 16 + lr) << 5) + sc;
            ah[f] = *(const half8v*)(&sm[ra]);
            bh[f] = *(const half8v*)(&sm[4096 + rb]);
        }
#pragma unroll
        for (int fm = 0; fm < 4; ++fm)
#pragma unroll
            for (int fn = 0; fn < 4; ++fn)
                acc[fm][fn] = __builtin_amdgcn_mfma_f32_16x16x32_f16(ah[fm], bh[fn], acc[fm][fn], 0, 0, 0);
        if (s + 1 < nsteps) CONVALL();
    }
#undef GLD
#undef CV8
#undef CONVALL

#pragma unroll
    for (int fm = 0; fm < 4; ++fm) {
#pragma unroll
        for (int j = 0; j < 4; ++j) {
            const int row = m0 + wr * 64 + fm * 16 + (l >> 4) * 4 + j;
            const size_t crow = (size_t)row * 512;
#pragma unroll
            for (int fn = 0; fn < 4; ++fn) {
                const int col = n0 + wc * 64 + fn * 16 + lr;
                float v = acc[fm][fn][j] * alpha;
                acc[fm][fn][j] = v;
                C[crow + col] = f2h(v);
            }
        }
    }

    if (ti != tj) {
        const int TP = 70;
        unsigned short* smT = sm;
        const int cst = wc * 64 + lr;
        const int r4  = (l >> 4) * 4;
        const int rc2 = t >> 1;
        const int chh = t & 1;
        __syncthreads();
#pragma unroll
        for (int h = 0; h < 2; ++h) {
            if (wr == h) {
#pragma unroll
                for (int fm = 0; fm < 4; ++fm) {
#pragma unroll
                    for (int fn = 0; fn < 4; ++fn) {
                        ushort4 q;
                        q.x = f2h(acc[fm][fn][0]);
                        q.y = f2h(acc[fm][fn][1]);
                        q.z = f2h(acc[fm][fn][2]);
                        q.w = f2h(acc[fm][fn][3]);
                        *(ushort4*)&smT[(cst + fn * 16) * TP + r4 + fm * 16] = q;
                    }
                }
            }
            __syncthreads();
            {
                unsigned short* dst = C + (size_t)(n0 + rc2) * 512 + m0 + h * 64 + chh * 32;
                const unsigned short* srcp = &smT[rc2 * TP + chh * 32];
#pragma unroll
                for (int k = 0; k < 8; ++k)
                    *(ushort4*)(dst + k * 4) = *(const ushort4*)(srcp + k * 4);
            }
            __syncthreads();
        }
    }
}

// ---------------------------------------------------------------------------
// Frobenius norm (fp16 plane), two-stage: 512-block partial + finish
// ---------------------------------------------------------------------------
__global__ __launch_bounds__(256) void frob_s(const unsigned short* __restrict__ P,
                                              float* __restrict__ pp)
{
    const int b = blockIdx.x >> 3, sg = blockIdx.x & 7;
    const unsigned short* p = P + (size_t)b * SLOT_S + sg * 32768;
    float s = 0.f;
    for (int i = threadIdx.x * 8; i < 32768; i += 2048) {
        ushort8v h = *(const ushort8v*)(p + i);
#pragma unroll
        for (int j = 0; j < 8; ++j) {
            float v = h2f(h[j]);
            s += v * v;
        }
    }
    __shared__ float red[256];
    red[threadIdx.x] = s;
    __syncthreads();
    for (int wd = 128; wd > 0; wd >>= 1) {
        if (threadIdx.x < wd) red[threadIdx.x] += red[threadIdx.x + wd];
        __syncthreads();
    }
    if (threadIdx.x == 0) pp[blockIdx.x] = red[0];
}

__global__ __launch_bounds__(64) void frob_fin(const float* __restrict__ pp,
                                               float* __restrict__ out)
{
    const int b = threadIdx.x;
    float s = 0.f;
#pragma unroll
    for (int i = 0; i < 8; ++i) s += pp[b * 8 + i];
    out[b] = sqrtf(s);
}

// ---------------------------------------------------------------------------
// FC via MFMA (fp16), k-split: grid 256 (128 sp x 2 nt). (round-12 verbatim)
// ---------------------------------------------------------------------------
__global__ __launch_bounds__(256) void fc_mfma_s(
    const unsigned short* __restrict__ Vp, const float* __restrict__ Wfc,
    float* __restrict__ part)
{
    __shared__ __align__(16) unsigned short sm2[6144];

    const int sp = blockIdx.x >> 1;
    const int nt = blockIdx.x & 1;
    const int kbase = sp * 2048;
    const int n0 = nt * 128;

    const int t = threadIdx.x;
    const int l = t & 63;
    const int w = t >> 6;
    const int wr = w >> 1, wc = w & 1;
    const int lr = l & 15;
    const int sc = (((l >> 4) ^ ((l >> 1) & 3)) << 3);

    const int sr = t >> 1, sh = t & 1;
    const int swz = (sr >> 1) & 3;
    const int slot0 = ((((sh << 1) | 0) ^ swz) << 3);
    const int slot1 = ((((sh << 1) | 1) ^ swz) << 3);

    const unsigned short* gA = Vp + (size_t)sr * SLOT_S + kbase + sh * 16;   // t<128
    const int wrow = n0 + sr;
    const bool wv = wrow < 200;
    const float* gB = Wfc + (size_t)wrow * 262144 + kbase + sh * 16;

    f32x4 acc[2][4] = {};

    ushort8v va0, va1, vb0, vb1;
    float4 wf0, wf1, wf2, wf3;
#define FLOAD(OFF) do { \
    if (t < 128) { \
        va0 = *(const ushort8v*)(gA + (OFF)); va1 = *(const ushort8v*)(gA + (OFF) + 8); \
    } \
    if (wv) { \
        wf0 = *(const float4*)(gB + (OFF));      wf1 = *(const float4*)(gB + (OFF) + 4); \
        wf2 = *(const float4*)(gB + (OFF) + 8);  wf3 = *(const float4*)(gB + (OFF) + 12); \
    } else { \
        wf0 = wf1 = wf2 = wf3 = make_float4(0.f, 0.f, 0.f, 0.f); \
    } \
    vb0[0] = f2h(wf0.x); vb0[1] = f2h(wf0.y); vb0[2] = f2h(wf0.z); vb0[3] = f2h(wf0.w); \
    vb0[4] = f2h(wf1.x); vb0[5] = f2h(wf1.y); vb0[6] = f2h(wf1.z); vb0[7] = f2h(wf1.w); \
    vb1[0] = f2h(wf2.x); vb1[1] = f2h(wf2.y); vb1[2] = f2h(wf2.z); vb1[3] = f2h(wf2.w); \
    vb1[4] = f2h(wf3.x); vb1[5] = f2h(wf3.y); vb1[6] = f2h(wf3.z); vb1[7] = f2h(wf3.w); \
  } while (0)

    FLOAD(0);
    for (int s = 0; s < 64; ++s) {
        __syncthreads();
        if (t < 128) {
            *(ushort8v*)&sm2[(sr << 5) + slot0] = va0;
            *(ushort8v*)&sm2[(sr << 5) + slot1] = va1;
        }
        *(ushort8v*)&sm2[2048 + (sr << 5) + slot0] = vb0;
        *(ushort8v*)&sm2[2048 + (sr << 5) + slot1] = vb1;
        __syncthreads();
        if (s + 1 < 64) FLOAD((s + 1) * 32);

        half8v ah[2], bh[4];
#pragma unroll
        for (int f = 0; f < 2; ++f) {
            const int ra = ((wr * 32 + f * 16 + lr) << 5) + sc;
            ah[f] = *(const half8v*)(&sm2[ra]);
        }
#pragma unroll
        for (int f = 0; f < 4; ++f) {
            const int rb = ((wc * 64 + f * 16 + lr) << 5) + sc;
            bh[f] = *(const half8v*)(&sm2[2048 + rb]);
        }
#pragma unroll
        for (int fm = 0; fm < 2; ++fm)
#pragma unroll
            for (int fn = 0; fn < 4; ++fn)
                acc[fm][fn] = __builtin_amdgcn_mfma_f32_16x16x32_f16(ah[fm], bh[fn], acc[fm][fn], 0, 0, 0);
    }
#undef FLOAD

    float* pb = part + (size_t)(sp * 2 + nt) * 64 * 128;
#pragma unroll
    for (int fm = 0; fm < 2; ++fm)
#pragma unroll
        for (int j = 0; j < 4; ++j) {
            const int row = wr * 32 + fm * 16 + (l >> 4) * 4 + j;
#pragma unroll
            for (int fn = 0; fn < 4; ++fn) {
                const int col = wc * 64 + fn * 16 + lr;
                pb[(size_t)row * 128 + col] = acc[fm][fn][j];
            }
        }
}

__global__ __launch_bounds__(256) void fc_reduce(
    const float* __restrict__ part, const float* __restrict__ n2,
    const float* __restrict__ bias, float* __restrict__ out)
{
    const int p = blockIdx.x * 256 + threadIdx.x;
    if (p >= 64 * 200) return;
    const int b = p / 200, o = p % 200;
    const int nt = o >> 7, n = o & 127;
    float s = 0.f;
    for (int c = 0; c < 128; ++c)
        s += part[((size_t)(c * 2 + nt) * 64 + b) * 128 + n];
    const float nb = fmaxf(n2[b], 1e-12f);
    out[p] = s / nb + bias[o];
}

// ---------------------------------------------------------------------------
extern "C" void kernel_launch(void* const* d_in, const int* in_sizes, int n_in,
                              void* d_out, int out_size, void* d_ws, size_t ws_size,
                              hipStream_t stream)
{
    const float* X    = (const float*)d_in[0];
    const float* Wfc  = (const float*)d_in[1];
    const float* bias = (const float*)d_in[2];
    float* out = (float*)d_out;

    float* norm  = (float*)d_ws;
    float* norm2 = norm + 64;
    float* fpart = norm2 + 64;                              // 512
    float* part  = fpart + 512;                             // 8 MiB
    unsigned short* region = (unsigned short*)(part + (size_t)256 * 64 * 128);

    unsigned short* P[4];
    for (int i = 0; i < 4; ++i) P[i] = region + (size_t)i * 64 * SLOT_S;

    // A = X X^T / 784 -> P0 (fp16); norm
    gram_single<<<640, 256, 0, stream>>>(X, P[0], 1.0f / 784.0f, 800);
    frob_s<<<512, 256, 0, stream>>>(P[0], fpart);
    frob_fin<<<1, 64, 0, stream>>>(fpart, norm);

    // NS, T applied as f32 epilogue affine. No init pass (modes 1/2).
    // it0a (mode 1): Y1 = rn*(1.5A - 0.5*rn*A@A) -> P2
    ns_single<<<640, 256, 0, stream>>>(P[0], P[0], P[0], P[2], P[2],
        512, (long)SLOT_S, 512, (long)SLOT_S, 512, 1, norm, 1);
    // it0b (mode 2): M1 = 1.5*Y1 - 0.5*rn*(Y1@A) -> P3
    ns_single<<<640, 256, 0, stream>>>(P[2], P[2], P[0], P[3], P[3],
        512, (long)SLOT_S, 512, (long)SLOT_S, 512, 2, norm, 1);

    unsigned short *Y = P[2], *M = P[3], *F0 = P[0], *F1 = P[1];
    for (int it = 1; it <= 8; ++it) {
        // s1 merged: z=0: U = M*T(M) -> F0 ; z=1: Ynew = Y*T(M) -> F1
        ns_single<<<1280, 256, 0, stream>>>(M, Y, M, F0, F1,
            512, (long)SLOT_S, 512, (long)SLOT_S, 512, 0, norm, 2);
        // s2: Mnew = U*T(M) -> old Y slot
        ns_single<<<640, 256, 0, stream>>>(F0, F0, M, Y, Y,
            512, (long)SLOT_S, 512, (long)SLOT_S, 512, 0, norm, 1);
        unsigned short* Mold = M;
        M = Y;        // Mnew lives in old Y slot
        Y = F1;       // Ynew
        F1 = Mold;    // Mold freed
    }
    // it9 (mode 3): V = sgn_sqrt((1.5Y - 0.5 Y@M) * sqrt(n)) -> F0
    ns_single<<<640, 256, 0, stream>>>(Y, Y, M, F0, F0,
        512, (long)SLOT_S, 512, (long)SLOT_S, 512, 3, norm, 1);

    // n2 = ||V||; FC head
    unsigned short* Vp = F0;
    frob_s<<<512, 256, 0, stream>>>(Vp, fpart);
    frob_fin<<<1, 64, 0, stream>>>(fpart, norm2);
    fc_mfma_s<<<dim3(256), 256, 0, stream>>>(Vp, Wfc, part);
    fc_reduce<<<50, 256, 0, stream>>>(part, norm2, bias, out);
}

// Round 16
// 1223.184 us; speedup vs baseline: 1.0925x; 1.0925x over previous
//
#include <hip/hip_runtime.h>
#include <math.h>
#include <stdint.h>

#define DIMM 512
#define SLOT_S 262144                    // single-plane slot per batch (ushorts) = 512 KiB

typedef __attribute__((ext_vector_type(8))) _Float16 half8v;
typedef __attribute__((ext_vector_type(8))) unsigned short ushort8v;
typedef __attribute__((ext_vector_type(4))) float f32x4;

__device__ __forceinline__ unsigned short f2h(float f) {
    _Float16 h = (_Float16)f;                       // v_cvt_f16_f32 (RNE)
    return __builtin_bit_cast(unsigned short, h);
}
__device__ __forceinline__ float h2f(unsigned short u) {
    return (float)__builtin_bit_cast(_Float16, u);  // v_cvt_f32_f16
}
__device__ __forceinline__ float sgn_sqrt(float tv)
{
    float r = sqrtf(fabsf(tv) + 1e-5f);
    return tv > 0.f ? r : (tv < 0.f ? -r : 0.f);
}

// ---------------------------------------------------------------------------
// fp16 NS GEMM — round-12 proven body (BK=32, 17920B LDS, raw B staging,
// f32 affine epilogue with A re-read) + epilogue-only modes.
// __launch_bounds__(256,4) pins VGPR <= 128: keeps 4 blocks/CU (the 129+
// VGPR cliff halves occupancy — r15's 34% regression).
//   base = 1.5*a - 0.5*kscale*acc
//   mode 0: kscale=1,  v = base                      (normal NS step)
//   mode 1: kscale=rn, v = rn*base                   (it0a: Y1 from raw A)
//   mode 2: kscale=rn, v = base                      (it0b: M1, B = raw A)
//   mode 3: kscale=1,  v = sgn_sqrt(base*sqrt(n))    (it9 + signed-sqrt)
// LDS XOR-chunk involution (r7/r9-validated); symmetric 10-tile + TP=70
// half-pass mirror (r9-validated); rolled K-loop; XCD remap. grid 640*nz.
// ---------------------------------------------------------------------------
__global__ __launch_bounds__(256, 4) void ns_single(
    const unsigned short* __restrict__ A0, const unsigned short* __restrict__ A1,
    const unsigned short* __restrict__ Bb,
    unsigned short* __restrict__ C0, unsigned short* __restrict__ C1,
    int lda, long aslot, int ldb, long bslot, int K,
    int mode, const float* __restrict__ norm, int nz)
{
    __shared__ __align__(16) unsigned short sm[8960];  // staging 8192; mirror 128x70

    const int nwg = gridDim.x;
    const int chunk = nwg >> 3;                   // nwg % 8 == 0
    const int bid = blockIdx.x;
    const int wu = (bid & 7) * chunk + (bid >> 3);
    const int per_batch = nz * 10;
    const int bz = wu / per_batch;
    const int rr = wu - bz * per_batch;
    const int z  = rr / 10;
    const int tile = rr - z * 10;
    int ti, tj;
    if (tile < 4)      { ti = 0; tj = tile; }
    else if (tile < 7) { ti = 1; tj = tile - 3; }
    else if (tile < 9) { ti = 2; tj = tile - 5; }
    else               { ti = 3; tj = 3; }

    const unsigned short* A  = (z ? A1 : A0) + (size_t)bz * aslot;
    const unsigned short* Bp = Bb + (size_t)bz * bslot;
    unsigned short* C = (z ? C1 : C0) + (size_t)bz * SLOT_S;

    float rn = 1.0f, sq = 0.0f;
    if (mode != 0) {
        const float nv = norm[bz];
        rn = 1.0f / nv;
        sq = sqrtf(nv);
    }
    const float kscale = (mode == 1 || mode == 2) ? rn : 1.0f;

    const int m0 = ti * 128;
    const int n0 = tj * 128;

    const int t = threadIdx.x;
    const int l = t & 63;
    const int w = t >> 6;
    const int wr = w >> 1, wc = w & 1;
    const int lr = l & 15;
    const int sc = (((l >> 4) ^ ((l >> 1) & 3)) << 3);   // swizzled read chunk

    // staging: thread covers row sr, global chunks {2sh, 2sh+1}; XOR'd slots
    const int sr = t >> 1, sh = t & 1;
    const int swz = (sr >> 1) & 3;
    const int slot0 = ((((sh << 1) | 0) ^ swz) << 3);
    const int slot1 = ((((sh << 1) | 1) ^ swz) << 3);
    const int wbase = sr * 32;
    const unsigned short* pA = A  + (size_t)(m0 + sr) * lda + sh * 16;
    const unsigned short* pB = Bp + (size_t)(n0 + sr) * ldb + sh * 16;

    f32x4 acc[4][4] = {};

    ushort8v a0, a1, b0, b1;
#define LOADALL(OFF) do { \
    a0 = *(const ushort8v*)(pA + (OFF));  a1 = *(const ushort8v*)(pA + (OFF) + 8); \
    b0 = *(const ushort8v*)(pB + (OFF));  b1 = *(const ushort8v*)(pB + (OFF) + 8); \
  } while (0)

    LOADALL(0);
    const int nsteps = K >> 5;
    for (int s = 0; s < nsteps; ++s) {
        __syncthreads();
        *(ushort8v*)&sm[       wbase + slot0] = a0; *(ushort8v*)&sm[       wbase + slot1] = a1;
        *(ushort8v*)&sm[4096 + wbase + slot0] = b0; *(ushort8v*)&sm[4096 + wbase + slot1] = b1;
        __syncthreads();
        if (s + 1 < nsteps) LOADALL((s + 1) * 32);

        half8v ah[4], bh[4];
#pragma unroll
        for (int f = 0; f < 4; ++f) {
            const int ra = ((wr * 64 + f * 16 + lr) << 5) + sc;
            const int rb = ((wc * 64 + f * 16 + lr) << 5) + sc;
            ah[f] = *(const half8v*)(&sm[ra]);
            bh[f] = *(const half8v*)(&sm[4096 + rb]);
        }
#pragma unroll
        for (int fm = 0; fm < 4; ++fm)
#pragma unroll
            for (int fn = 0; fn < 4; ++fn)
                acc[fm][fn] = __builtin_amdgcn_mfma_f32_16x16x32_f16(ah[fm], bh[fn], acc[fm][fn], 0, 0, 0);
    }
#undef LOADALL

    // epilogue (f32 affine): base = 1.5a - 0.5*kscale*acc; write upper tile
    // C/D layout: col = lane&15, row = (lane>>4)*4 + reg  [m89-verified]
#pragma unroll
    for (int fm = 0; fm < 4; ++fm) {
#pragma unroll
        for (int j = 0; j < 4; ++j) {
            const int row = m0 + wr * 64 + fm * 16 + (l >> 4) * 4 + j;
            const unsigned short* arow = A + (size_t)row * lda;
            const size_t crow = (size_t)row * 512;
#pragma unroll
            for (int fn = 0; fn < 4; ++fn) {
                const int col = n0 + wc * 64 + fn * 16 + lr;
                float v = 1.5f * h2f(arow[col]) - 0.5f * kscale * acc[fm][fn][j];
                if (mode == 1) v *= rn;
                else if (mode == 3) v = sgn_sqrt(v * sq);
                acc[fm][fn][j] = v;
                C[crow + col] = f2h(v);
            }
        }
    }

    // mirrored (lower) tile: two 64-row half-pass LDS transposes (TP=70)
    if (ti != tj) {
        const int TP = 70;
        unsigned short* smT = sm;
        const int cst = wc * 64 + lr;
        const int r4  = (l >> 4) * 4;
        const int rc2 = t >> 1;
        const int chh = t & 1;
        __syncthreads();
#pragma unroll
        for (int h = 0; h < 2; ++h) {
            if (wr == h) {
#pragma unroll
                for (int fm = 0; fm < 4; ++fm) {
#pragma unroll
                    for (int fn = 0; fn < 4; ++fn) {
                        ushort4 q;
                        q.x = f2h(acc[fm][fn][0]);
                        q.y = f2h(acc[fm][fn][1]);
                        q.z = f2h(acc[fm][fn][2]);
                        q.w = f2h(acc[fm][fn][3]);
                        *(ushort4*)&smT[(cst + fn * 16) * TP + r4 + fm * 16] = q;
                    }
                }
            }
            __syncthreads();
            {
                unsigned short* dst = C + (size_t)(n0 + rc2) * 512 + m0 + h * 64 + chh * 32;
                const unsigned short* srcp = &smT[rc2 * TP + chh * 32];
#pragma unroll
                for (int k = 0; k < 8; ++k)
                    *(ushort4*)(dst + k * 4) = *(const ushort4*)(srcp + k * 4);
            }
            __syncthreads();
        }
    }
}

// ---------------------------------------------------------------------------
// Gram single-fp16 (round-12 verbatim): C = (X X^T)/784, conversion fused
// into staging; symmetric 10-tile + mirror; K=800, BK=32.
// ---------------------------------------------------------------------------
__global__ __launch_bounds__(256) void gram_single(const float* __restrict__ X,
                                                   unsigned short* __restrict__ C0,
                                                   float alpha, int K)
{
    __shared__ __align__(16) unsigned short sm[8960];

    const int nwg = gridDim.x;
    const int chunk = nwg >> 3;
    const int wu = (blockIdx.x & 7) * chunk + (blockIdx.x >> 3);
    const int bz = wu / 10, tile = wu - bz * 10;
    int ti, tj;
    if (tile < 4)      { ti = 0; tj = tile; }
    else if (tile < 7) { ti = 1; tj = tile - 3; }
    else if (tile < 9) { ti = 2; tj = tile - 5; }
    else               { ti = 3; tj = 3; }
    const int m0 = ti * 128, n0 = tj * 128;
    unsigned short* C = C0 + (size_t)bz * SLOT_S;

    const int t = threadIdx.x;
    const int l = t & 63;
    const int w = t >> 6;
    const int wr = w >> 1, wc = w & 1;
    const int lr = l & 15;
    const int sc = (((l >> 4) ^ ((l >> 1) & 3)) << 3);

    const int sr = t >> 1, sh = t & 1;
    const int swz = (sr >> 1) & 3;
    const int slot0 = ((((sh << 1) | 0) ^ swz) << 3);
    const int slot1 = ((((sh << 1) | 1) ^ swz) << 3);
    const int wbase = sr * 32;

    const float* pXa = X + ((size_t)bz * 512 + m0 + sr) * 784 + sh * 16;
    const float* pXb = X + ((size_t)bz * 512 + n0 + sr) * 784 + sh * 16;

    f32x4 acc[4][4] = {};

    float4 xa0, xa1, xa2, xa3, xb0, xb1, xb2, xb3;
    ushort8v a0, a1, b0, b1;

#define GLD(OFF) do { \
    if ((OFF) + sh * 16 < 784) { \
        xa0 = *(const float4*)(pXa + (OFF));      xa1 = *(const float4*)(pXa + (OFF) + 4); \
        xa2 = *(const float4*)(pXa + (OFF) + 8);  xa3 = *(const float4*)(pXa + (OFF) + 12); \
        xb0 = *(const float4*)(pXb + (OFF));      xb1 = *(const float4*)(pXb + (OFF) + 4); \
        xb2 = *(const float4*)(pXb + (OFF) + 8);  xb3 = *(const float4*)(pXb + (OFF) + 12); \
    } else { \
        xa0 = xa1 = xa2 = xa3 = make_float4(0.f, 0.f, 0.f, 0.f); \
        xb0 = xb1 = xb2 = xb3 = make_float4(0.f, 0.f, 0.f, 0.f); \
    } } while (0)

#define CV8(F0, F1, O) do { \
    (O)[0] = f2h((F0).x); (O)[1] = f2h((F0).y); \
    (O)[2] = f2h((F0).z); (O)[3] = f2h((F0).w); \
    (O)[4] = f2h((F1).x); (O)[5] = f2h((F1).y); \
    (O)[6] = f2h((F1).z); (O)[7] = f2h((F1).w); \
  } while (0)

#define CONVALL() do { \
    CV8(xa0, xa1, a0); CV8(xa2, xa3, a1); \
    CV8(xb0, xb1, b0); CV8(xb2, xb3, b1); \
  } while (0)

    GLD(0);
    CONVALL();
    const int nsteps = K >> 5;
    for (int s = 0; s < nsteps; ++s) {
        __syncthreads();
        *(ushort8v*)&sm[       wbase + slot0] = a0; *(ushort8v*)&sm[       wbase + slot1] = a1;
        *(ushort8v*)&sm[4096 + wbase + slot0] = b0; *(ushort8v*)&sm[4096 + wbase + slot1] = b1;
        __syncthreads();
        if (s + 1 < nsteps) GLD((s + 1) * 32);

        half8v ah[4], bh[4];
#pragma unroll
        for (int f = 0; f < 4; ++f) {
            const int ra = ((wr * 64 + f * 16 + lr) << 5) + sc;
            const int rb = ((wc * 64 + f * 16 + lr) << 5) + sc;
            ah[f] = *(const half8v*)(&sm[ra]);
            bh[f] = *(const half8v*)(&sm[4096 + rb]);
        }
#pragma unroll
        for (int fm = 0; fm < 4; ++fm)
#pragma unroll
            for (int fn = 0; fn < 4; ++fn)
                acc[fm][fn] = __builtin_amdgcn_mfma_f32_16x16x32_f16(ah[fm], bh[fn], acc[fm][fn], 0, 0, 0);
        if (s + 1 < nsteps) CONVALL();
    }
#undef GLD
#undef CV8
#undef CONVALL

#pragma unroll
    for (int fm = 0; fm < 4; ++fm) {
#pragma unroll
        for (int j = 0; j < 4; ++j) {
            const int row = m0 + wr * 64 + fm * 16 + (l >> 4) * 4 + j;
            const size_t crow = (size_t)row * 512;
#pragma unroll
            for (int fn = 0; fn < 4; ++fn) {
                const int col = n0 + wc * 64 + fn * 16 + lr;
                float v = acc[fm][fn][j] * alpha;
                acc[fm][fn][j] = v;
                C[crow + col] = f2h(v);
            }
        }
    }

    if (ti != tj) {
        const int TP = 70;
        unsigned short* smT = sm;
        const int cst = wc * 64 + lr;
        const int r4  = (l >> 4) * 4;
        const int rc2 = t >> 1;
        const int chh = t & 1;
        __syncthreads();
#pragma unroll
        for (int h = 0; h < 2; ++h) {
            if (wr == h) {
#pragma unroll
                for (int fm = 0; fm < 4; ++fm) {
#pragma unroll
                    for (int fn = 0; fn < 4; ++fn) {
                        ushort4 q;
                        q.x = f2h(acc[fm][fn][0]);
                        q.y = f2h(acc[fm][fn][1]);
                        q.z = f2h(acc[fm][fn][2]);
                        q.w = f2h(acc[fm][fn][3]);
                        *(ushort4*)&smT[(cst + fn * 16) * TP + r4 + fm * 16] = q;
                    }
                }
            }
            __syncthreads();
            {
                unsigned short* dst = C + (size_t)(n0 + rc2) * 512 + m0 + h * 64 + chh * 32;
                const unsigned short* srcp = &smT[rc2 * TP + chh * 32];
#pragma unroll
                for (int k = 0; k < 8; ++k)
                    *(ushort4*)(dst + k * 4) = *(const ushort4*)(srcp + k * 4);
            }
            __syncthreads();
        }
    }
}

// ---------------------------------------------------------------------------
// Frobenius norm (fp16 plane), two-stage: 512-block partial + finish
// ---------------------------------------------------------------------------
__global__ __launch_bounds__(256) void frob_s(const unsigned short* __restrict__ P,
                                              float* __restrict__ pp)
{
    const int b = blockIdx.x >> 3, sg = blockIdx.x & 7;
    const unsigned short* p = P + (size_t)b * SLOT_S + sg * 32768;
    float s = 0.f;
    for (int i = threadIdx.x * 8; i < 32768; i += 2048) {
        ushort8v h = *(const ushort8v*)(p + i);
#pragma unroll
        for (int j = 0; j < 8; ++j) {
            float v = h2f(h[j]);
            s += v * v;
        }
    }
    __shared__ float red[256];
    red[threadIdx.x] = s;
    __syncthreads();
    for (int wd = 128; wd > 0; wd >>= 1) {
        if (threadIdx.x < wd) red[threadIdx.x] += red[threadIdx.x + wd];
        __syncthreads();
    }
    if (threadIdx.x == 0) pp[blockIdx.x] = red[0];
}

__global__ __launch_bounds__(64) void frob_fin(const float* __restrict__ pp,
                                               float* __restrict__ out)
{
    const int b = threadIdx.x;
    float s = 0.f;
#pragma unroll
    for (int i = 0; i < 8; ++i) s += pp[b * 8 + i];
    out[b] = sqrtf(s);
}

// ---------------------------------------------------------------------------
// FC via MFMA (fp16), k-split: grid 256 (128 sp x 2 nt). (round-12 verbatim)
// ---------------------------------------------------------------------------
__global__ __launch_bounds__(256) void fc_mfma_s(
    const unsigned short* __restrict__ Vp, const float* __restrict__ Wfc,
    float* __restrict__ part)
{
    __shared__ __align__(16) unsigned short sm2[6144];

    const int sp = blockIdx.x >> 1;
    const int nt = blockIdx.x & 1;
    const int kbase = sp * 2048;
    const int n0 = nt * 128;

    const int t = threadIdx.x;
    const int l = t & 63;
    const int w = t >> 6;
    const int wr = w >> 1, wc = w & 1;
    const int lr = l & 15;
    const int sc = (((l >> 4) ^ ((l >> 1) & 3)) << 3);

    const int sr = t >> 1, sh = t & 1;
    const int swz = (sr >> 1) & 3;
    const int slot0 = ((((sh << 1) | 0) ^ swz) << 3);
    const int slot1 = ((((sh << 1) | 1) ^ swz) << 3);

    const unsigned short* gA = Vp + (size_t)sr * SLOT_S + kbase + sh * 16;   // t<128
    const int wrow = n0 + sr;
    const bool wv = wrow < 200;
    const float* gB = Wfc + (size_t)wrow * 262144 + kbase + sh * 16;

    f32x4 acc[2][4] = {};

    ushort8v va0, va1, vb0, vb1;
    float4 wf0, wf1, wf2, wf3;
#define FLOAD(OFF) do { \
    if (t < 128) { \
        va0 = *(const ushort8v*)(gA + (OFF)); va1 = *(const ushort8v*)(gA + (OFF) + 8); \
    } \
    if (wv) { \
        wf0 = *(const float4*)(gB + (OFF));      wf1 = *(const float4*)(gB + (OFF) + 4); \
        wf2 = *(const float4*)(gB + (OFF) + 8);  wf3 = *(const float4*)(gB + (OFF) + 12); \
    } else { \
        wf0 = wf1 = wf2 = wf3 = make_float4(0.f, 0.f, 0.f, 0.f); \
    } \
    vb0[0] = f2h(wf0.x); vb0[1] = f2h(wf0.y); vb0[2] = f2h(wf0.z); vb0[3] = f2h(wf0.w); \
    vb0[4] = f2h(wf1.x); vb0[5] = f2h(wf1.y); vb0[6] = f2h(wf1.z); vb0[7] = f2h(wf1.w); \
    vb1[0] = f2h(wf2.x); vb1[1] = f2h(wf2.y); vb1[2] = f2h(wf2.z); vb1[3] = f2h(wf2.w); \
    vb1[4] = f2h(wf3.x); vb1[5] = f2h(wf3.y); vb1[6] = f2h(wf3.z); vb1[7] = f2h(wf3.w); \
  } while (0)

    FLOAD(0);
    for (int s = 0; s < 64; ++s) {
        __syncthreads();
        if (t < 128) {
            *(ushort8v*)&sm2[(sr << 5) + slot0] = va0;
            *(ushort8v*)&sm2[(sr << 5) + slot1] = va1;
        }
        *(ushort8v*)&sm2[2048 + (sr << 5) + slot0] = vb0;
        *(ushort8v*)&sm2[2048 + (sr << 5) + slot1] = vb1;
        __syncthreads();
        if (s + 1 < 64) FLOAD((s + 1) * 32);

        half8v ah[2], bh[4];
#pragma unroll
        for (int f = 0; f < 2; ++f) {
            const int ra = ((wr * 32 + f * 16 + lr) << 5) + sc;
            ah[f] = *(const half8v*)(&sm2[ra]);
        }
#pragma unroll
        for (int f = 0; f < 4; ++f) {
            const int rb = ((wc * 64 + f * 16 + lr) << 5) + sc;
            bh[f] = *(const half8v*)(&sm2[2048 + rb]);
        }
#pragma unroll
        for (int fm = 0; fm < 2; ++fm)
#pragma unroll
            for (int fn = 0; fn < 4; ++fn)
                acc[fm][fn] = __builtin_amdgcn_mfma_f32_16x16x32_f16(ah[fm], bh[fn], acc[fm][fn], 0, 0, 0);
    }
#undef FLOAD

    float* pb = part + (size_t)(sp * 2 + nt) * 64 * 128;
#pragma unroll
    for (int fm = 0; fm < 2; ++fm)
#pragma unroll
        for (int j = 0; j < 4; ++j) {
            const int row = wr * 32 + fm * 16 + (l >> 4) * 4 + j;
#pragma unroll
            for (int fn = 0; fn < 4; ++fn) {
                const int col = wc * 64 + fn * 16 + lr;
                pb[(size_t)row * 128 + col] = acc[fm][fn][j];
            }
        }
}

__global__ __launch_bounds__(256) void fc_reduce(
    const float* __restrict__ part, const float* __restrict__ n2,
    const float* __restrict__ bias, float* __restrict__ out)
{
    const int p = blockIdx.x * 256 + threadIdx.x;
    if (p >= 64 * 200) return;
    const int b = p / 200, o = p % 200;
    const int nt = o >> 7, n = o & 127;
    float s = 0.f;
    for (int c = 0; c < 128; ++c)
        s += part[((size_t)(c * 2 + nt) * 64 + b) * 128 + n];
    const float nb = fmaxf(n2[b], 1e-12f);
    out[p] = s / nb + bias[o];
}

// ---------------------------------------------------------------------------
extern "C" void kernel_launch(void* const* d_in, const int* in_sizes, int n_in,
                              void* d_out, int out_size, void* d_ws, size_t ws_size,
                              hipStream_t stream)
{
    const float* X    = (const float*)d_in[0];
    const float* Wfc  = (const float*)d_in[1];
    const float* bias = (const float*)d_in[2];
    float* out = (float*)d_out;

    float* norm  = (float*)d_ws;
    float* norm2 = norm + 64;
    float* fpart = norm2 + 64;                              // 512
    float* part  = fpart + 512;                             // 8 MiB
    unsigned short* region = (unsigned short*)(part + (size_t)256 * 64 * 128);

    unsigned short* P[4];
    for (int i = 0; i < 4; ++i) P[i] = region + (size_t)i * 64 * SLOT_S;

    // A = X X^T / 784 -> P0 (fp16); norm
    gram_single<<<640, 256, 0, stream>>>(X, P[0], 1.0f / 784.0f, 800);
    frob_s<<<512, 256, 0, stream>>>(P[0], fpart);
    frob_fin<<<1, 64, 0, stream>>>(fpart, norm);

    // NS, T applied as f32 epilogue affine. No init pass (modes 1/2).
    // it0a (mode 1): Y1 = rn*(1.5A - 0.5*rn*A@A) -> P2
    ns_single<<<640, 256, 0, stream>>>(P[0], P[0], P[0], P[2], P[2],
        512, (long)SLOT_S, 512, (long)SLOT_S, 512, 1, norm, 1);
    // it0b (mode 2): M1 = 1.5*Y1 - 0.5*rn*(Y1@A) -> P3
    ns_single<<<640, 256, 0, stream>>>(P[2], P[2], P[0], P[3], P[3],
        512, (long)SLOT_S, 512, (long)SLOT_S, 512, 2, norm, 1);

    unsigned short *Y = P[2], *M = P[3], *F0 = P[0], *F1 = P[1];
    for (int it = 1; it <= 8; ++it) {
        // s1 merged: z=0: U = M*T(M) -> F0 ; z=1: Ynew = Y*T(M) -> F1
        ns_single<<<1280, 256, 0, stream>>>(M, Y, M, F0, F1,
            512, (long)SLOT_S, 512, (long)SLOT_S, 512, 0, norm, 2);
        // s2: Mnew = U*T(M) -> old Y slot
        ns_single<<<640, 256, 0, stream>>>(F0, F0, M, Y, Y,
            512, (long)SLOT_S, 512, (long)SLOT_S, 512, 0, norm, 1);
        unsigned short* Mold = M;
        M = Y;        // Mnew lives in old Y slot
        Y = F1;       // Ynew
        F1 = Mold;    // Mold freed
    }
    // it9 (mode 3): V = sgn_sqrt((1.5Y - 0.5 Y@M) * sqrt(n)) -> F0
    ns_single<<<640, 256, 0, stream>>>(Y, Y, M, F0, F0,
        512, (long)SLOT_S, 512, (long)SLOT_S, 512, 3, norm, 1);

    // n2 = ||V||; FC head
    unsigned short* Vp = F0;
    frob_s<<<512, 256, 0, stream>>>(Vp, fpart);
    frob_fin<<<1, 64, 0, stream>>>(fpart, norm2);
    fc_mfma_s<<<dim3(256), 256, 0, stream>>>(Vp, Wfc, part);
    fc_reduce<<<50, 256, 0, stream>>>(part, norm2, bias, out);
}

// Round 17
// 993.130 us; speedup vs baseline: 1.3455x; 1.2316x over previous
//
#include <hip/hip_runtime.h>
#include <math.h>
#include <stdint.h>

#define DIMM 512
#define SLOT_S 262144                    // single-plane slot per batch (ushorts) = 512 KiB

typedef __attribute__((ext_vector_type(8))) _Float16 half8v;
typedef __attribute__((ext_vector_type(8))) unsigned short ushort8v;
typedef __attribute__((ext_vector_type(4))) float f32x4;

__device__ __forceinline__ unsigned short f2h(float f) {
    _Float16 h = (_Float16)f;                       // v_cvt_f16_f32 (RNE)
    return __builtin_bit_cast(unsigned short, h);
}
__device__ __forceinline__ float h2f(unsigned short u) {
    return (float)__builtin_bit_cast(_Float16, u);  // v_cvt_f32_f16
}
__device__ __forceinline__ float sgn_sqrt(float tv)
{
    float r = sqrtf(fabsf(tv) + 1e-5f);
    return tv > 0.f ? r : (tv < 0.f ? -r : 0.f);
}

// ---------------------------------------------------------------------------
// Single-fp16 NS GEMM. C = 1.5*A - 0.5*(A @ B^T-as-cols), operands fp16,
// fp32 MFMA accum. Symmetric 10-tile + TP=70 half-pass mirror (r9-validated).
// LDS: 2 planes x 128 rows x 32 ushorts, XOR-chunk involution slot =
// g ^ ((row>>1)&3) on write and read (r7/r9-validated). Rolled K-loop via
// runtime geometry. XCD-aware remap. grid 640*nz.  [round-12 measured best]
// ---------------------------------------------------------------------------
__global__ __launch_bounds__(256) void ns_single(
    const unsigned short* __restrict__ A0, const unsigned short* __restrict__ A1,
    const unsigned short* __restrict__ Bb,
    unsigned short* __restrict__ C0, unsigned short* __restrict__ C1,
    int lda, long aslot, int ldb, long bslot, int K, int nz)
{
    __shared__ __align__(16) unsigned short sm[8960];  // staging 8192; mirror 128x70

    const int nwg = gridDim.x;
    const int chunk = nwg >> 3;                   // nwg % 8 == 0
    const int bid = blockIdx.x;
    const int wu = (bid & 7) * chunk + (bid >> 3);
    const int per_batch = nz * 10;
    const int bz = wu / per_batch;
    const int rr = wu - bz * per_batch;
    const int z  = rr / 10;
    const int tile = rr - z * 10;
    int ti, tj;
    if (tile < 4)      { ti = 0; tj = tile; }
    else if (tile < 7) { ti = 1; tj = tile - 3; }
    else if (tile < 9) { ti = 2; tj = tile - 5; }
    else               { ti = 3; tj = 3; }

    const unsigned short* A  = (z ? A1 : A0) + (size_t)bz * aslot;
    const unsigned short* Bp = Bb + (size_t)bz * bslot;
    unsigned short* C = (z ? C1 : C0) + (size_t)bz * SLOT_S;

    const int m0 = ti * 128;
    const int n0 = tj * 128;

    const int t = threadIdx.x;
    const int l = t & 63;
    const int w = t >> 6;
    const int wr = w >> 1, wc = w & 1;
    const int lr = l & 15;
    const int sc = (((l >> 4) ^ ((l >> 1) & 3)) << 3);   // swizzled read chunk

    // staging: thread covers row sr, global chunks {2sh, 2sh+1}; XOR'd slots
    const int sr = t >> 1, sh = t & 1;
    const int swz = (sr >> 1) & 3;
    const int slot0 = ((((sh << 1) | 0) ^ swz) << 3);
    const int slot1 = ((((sh << 1) | 1) ^ swz) << 3);
    const int wbase = sr * 32;
    const unsigned short* pA = A  + (size_t)(m0 + sr) * lda + sh * 16;
    const unsigned short* pB = Bp + (size_t)(n0 + sr) * ldb + sh * 16;

    f32x4 acc[4][4] = {};

    ushort8v a0, a1, b0, b1;
#define LOADALL(OFF) do { \
    a0 = *(const ushort8v*)(pA + (OFF));  a1 = *(const ushort8v*)(pA + (OFF) + 8); \
    b0 = *(const ushort8v*)(pB + (OFF));  b1 = *(const ushort8v*)(pB + (OFF) + 8); \
  } while (0)

    LOADALL(0);
    const int nsteps = K >> 5;
    for (int s = 0; s < nsteps; ++s) {
        __syncthreads();
        *(ushort8v*)&sm[       wbase + slot0] = a0; *(ushort8v*)&sm[       wbase + slot1] = a1;
        *(ushort8v*)&sm[4096 + wbase + slot0] = b0; *(ushort8v*)&sm[4096 + wbase + slot1] = b1;
        __syncthreads();
        if (s + 1 < nsteps) LOADALL((s + 1) * 32);

        half8v ah[4], bh[4];
#pragma unroll
        for (int f = 0; f < 4; ++f) {
            const int ra = ((wr * 64 + f * 16 + lr) << 5) + sc;
            const int rb = ((wc * 64 + f * 16 + lr) << 5) + sc;
            ah[f] = *(const half8v*)(&sm[ra]);
            bh[f] = *(const half8v*)(&sm[4096 + rb]);
        }
#pragma unroll
        for (int fm = 0; fm < 4; ++fm)
#pragma unroll
            for (int fn = 0; fn < 4; ++fn)
                acc[fm][fn] = __builtin_amdgcn_mfma_f32_16x16x32_f16(ah[fm], bh[fn], acc[fm][fn], 0, 0, 0);
    }
#undef LOADALL

    // epilogue: v = 1.5*A - 0.5*acc; write upper tile
    // C/D layout: col = lane&15, row = (lane>>4)*4 + reg  [m89-verified]
#pragma unroll
    for (int fm = 0; fm < 4; ++fm) {
#pragma unroll
        for (int j = 0; j < 4; ++j) {
            const int row = m0 + wr * 64 + fm * 16 + (l >> 4) * 4 + j;
            const unsigned short* arow = A + (size_t)row * lda;
            const size_t crow = (size_t)row * 512;
#pragma unroll
            for (int fn = 0; fn < 4; ++fn) {
                const int col = n0 + wc * 64 + fn * 16 + lr;
                float v = 1.5f * h2f(arow[col]) - 0.5f * acc[fm][fn][j];
                acc[fm][fn][j] = v;
                C[crow + col] = f2h(v);
            }
        }
    }

    // mirrored (lower) tile: two 64-row half-pass LDS transposes (TP=70)
    if (ti != tj) {
        const int TP = 70;
        unsigned short* smT = sm;
        const int cst = wc * 64 + lr;
        const int r4  = (l >> 4) * 4;
        const int rc2 = t >> 1;
        const int chh = t & 1;
        __syncthreads();
#pragma unroll
        for (int h = 0; h < 2; ++h) {
            if (wr == h) {
#pragma unroll
                for (int fm = 0; fm < 4; ++fm) {
#pragma unroll
                    for (int fn = 0; fn < 4; ++fn) {
                        ushort4 q;
                        q.x = f2h(acc[fm][fn][0]);
                        q.y = f2h(acc[fm][fn][1]);
                        q.z = f2h(acc[fm][fn][2]);
                        q.w = f2h(acc[fm][fn][3]);
                        *(ushort4*)&smT[(cst + fn * 16) * TP + r4 + fm * 16] = q;
                    }
                }
            }
            __syncthreads();
            {
                unsigned short* dst = C + (size_t)(n0 + rc2) * 512 + m0 + h * 64 + chh * 32;
                const unsigned short* srcp = &smT[rc2 * TP + chh * 32];
#pragma unroll
                for (int k = 0; k < 8; ++k)
                    *(ushort4*)(dst + k * 4) = *(const ushort4*)(srcp + k * 4);
            }
            __syncthreads();
        }
    }
}

// ---------------------------------------------------------------------------
// Gram single-fp16: C = (X X^T)/784, fp32->fp16 conversion fused into staging
// (after MFMA block, overlapped). Symmetric 10-tile + mirror. K=800.
// ---------------------------------------------------------------------------
__global__ __launch_bounds__(256) void gram_single(const float* __restrict__ X,
                                                   unsigned short* __restrict__ C0,
                                                   float alpha, int K)
{
    __shared__ __align__(16) unsigned short sm[8960];

    const int nwg = gridDim.x;
    const int chunk = nwg >> 3;
    const int wu = (blockIdx.x & 7) * chunk + (blockIdx.x >> 3);
    const int bz = wu / 10, tile = wu - bz * 10;
    int ti, tj;
    if (tile < 4)      { ti = 0; tj = tile; }
    else if (tile < 7) { ti = 1; tj = tile - 3; }
    else if (tile < 9) { ti = 2; tj = tile - 5; }
    else               { ti = 3; tj = 3; }
    const int m0 = ti * 128, n0 = tj * 128;
    unsigned short* C = C0 + (size_t)bz * SLOT_S;

    const int t = threadIdx.x;
    const int l = t & 63;
    const int w = t >> 6;
    const int wr = w >> 1, wc = w & 1;
    const int lr = l & 15;
    const int sc = (((l >> 4) ^ ((l >> 1) & 3)) << 3);

    const int sr = t >> 1, sh = t & 1;
    const int swz = (sr >> 1) & 3;
    const int slot0 = ((((sh << 1) | 0) ^ swz) << 3);
    const int slot1 = ((((sh << 1) | 1) ^ swz) << 3);
    const int wbase = sr * 32;

    const float* pXa = X + ((size_t)bz * 512 + m0 + sr) * 784 + sh * 16;
    const float* pXb = X + ((size_t)bz * 512 + n0 + sr) * 784 + sh * 16;

    f32x4 acc[4][4] = {};

    float4 xa0, xa1, xa2, xa3, xb0, xb1, xb2, xb3;
    ushort8v a0, a1, b0, b1;

#define GLD(OFF) do { \
    if ((OFF) + sh * 16 < 784) { \
        xa0 = *(const float4*)(pXa + (OFF));      xa1 = *(const float4*)(pXa + (OFF) + 4); \
        xa2 = *(const float4*)(pXa + (OFF) + 8);  xa3 = *(const float4*)(pXa + (OFF) + 12); \
        xb0 = *(const float4*)(pXb + (OFF));      xb1 = *(const float4*)(pXb + (OFF) + 4); \
        xb2 = *(const float4*)(pXb + (OFF) + 8);  xb3 = *(const float4*)(pXb + (OFF) + 12); \
    } else { \
        xa0 = xa1 = xa2 = xa3 = make_float4(0.f, 0.f, 0.f, 0.f); \
        xb0 = xb1 = xb2 = xb3 = make_float4(0.f, 0.f, 0.f, 0.f); \
    } } while (0)

#define CV8(F0, F1, O) do { \
    (O)[0] = f2h((F0).x); (O)[1] = f2h((F0).y); \
    (O)[2] = f2h((F0).z); (O)[3] = f2h((F0).w); \
    (O)[4] = f2h((F1).x); (O)[5] = f2h((F1).y); \
    (O)[6] = f2h((F1).z); (O)[7] = f2h((F1).w); \
  } while (0)

#define CONVALL() do { \
    CV8(xa0, xa1, a0); CV8(xa2, xa3, a1); \
    CV8(xb0, xb1, b0); CV8(xb2, xb3, b1); \
  } while (0)

    GLD(0);
    CONVALL();
    const int nsteps = K >> 5;
    for (int s = 0; s < nsteps; ++s) {
        __syncthreads();
        *(ushort8v*)&sm[       wbase + slot0] = a0; *(ushort8v*)&sm[       wbase + slot1] = a1;
        *(ushort8v*)&sm[4096 + wbase + slot0] = b0; *(ushort8v*)&sm[4096 + wbase + slot1] = b1;
        __syncthreads();
        if (s + 1 < nsteps) GLD((s + 1) * 32);

        half8v ah[4], bh[4];
#pragma unroll
        for (int f = 0; f < 4; ++f) {
            const int ra = ((wr * 64 + f * 16 + lr) << 5) + sc;
            const int rb = ((wc * 64 + f * 16 + lr) << 5) + sc;
            ah[f] = *(const half8v*)(&sm[ra]);
            bh[f] = *(const half8v*)(&sm[4096 + rb]);
        }
#pragma unroll
        for (int fm = 0; fm < 4; ++fm)
#pragma unroll
            for (int fn = 0; fn < 4; ++fn)
                acc[fm][fn] = __builtin_amdgcn_mfma_f32_16x16x32_f16(ah[fm], bh[fn], acc[fm][fn], 0, 0, 0);
        if (s + 1 < nsteps) CONVALL();
    }
#undef GLD
#undef CV8
#undef CONVALL

#pragma unroll
    for (int fm = 0; fm < 4; ++fm) {
#pragma unroll
        for (int j = 0; j < 4; ++j) {
            const int row = m0 + wr * 64 + fm * 16 + (l >> 4) * 4 + j;
            const size_t crow = (size_t)row * 512;
#pragma unroll
            for (int fn = 0; fn < 4; ++fn) {
                const int col = n0 + wc * 64 + fn * 16 + lr;
                float v = acc[fm][fn][j] * alpha;
                acc[fm][fn][j] = v;
                C[crow + col] = f2h(v);
            }
        }
    }

    if (ti != tj) {
        const int TP = 70;
        unsigned short* smT = sm;
        const int cst = wc * 64 + lr;
        const int r4  = (l >> 4) * 4;
        const int rc2 = t >> 1;
        const int chh = t & 1;
        __syncthreads();
#pragma unroll
        for (int h = 0; h < 2; ++h) {
            if (wr == h) {
#pragma unroll
                for (int fm = 0; fm < 4; ++fm) {
#pragma unroll
                    for (int fn = 0; fn < 4; ++fn) {
                        ushort4 q;
                        q.x = f2h(acc[fm][fn][0]);
                        q.y = f2h(acc[fm][fn][1]);
                        q.z = f2h(acc[fm][fn][2]);
                        q.w = f2h(acc[fm][fn][3]);
                        *(ushort4*)&smT[(cst + fn * 16) * TP + r4 + fm * 16] = q;
                    }
                }
            }
            __syncthreads();
            {
                unsigned short* dst = C + (size_t)(n0 + rc2) * 512 + m0 + h * 64 + chh * 32;
                const unsigned short* srcp = &smT[rc2 * TP + chh * 32];
#pragma unroll
                for (int k = 0; k < 8; ++k)
                    *(ushort4*)(dst + k * 4) = *(const ushort4*)(srcp + k * 4);
            }
            __syncthreads();
        }
    }
}

// ---------------------------------------------------------------------------
// Frobenius norm (fp16 plane), two-stage: 512-block partial + finish
// ---------------------------------------------------------------------------
__global__ __launch_bounds__(256) void frob_s(const unsigned short* __restrict__ P,
                                              float* __restrict__ pp)
{
    const int b = blockIdx.x >> 3, sg = blockIdx.x & 7;
    const unsigned short* p = P + (size_t)b * SLOT_S + sg * 32768;
    float s = 0.f;
    for (int i = threadIdx.x * 8; i < 32768; i += 2048) {
        ushort8v h = *(const ushort8v*)(p + i);
#pragma unroll
        for (int j = 0; j < 8; ++j) {
            float v = h2f(h[j]);
            s += v * v;
        }
    }
    __shared__ float red[256];
    red[threadIdx.x] = s;
    __syncthreads();
    for (int wd = 128; wd > 0; wd >>= 1) {
        if (threadIdx.x < wd) red[threadIdx.x] += red[threadIdx.x + wd];
        __syncthreads();
    }
    if (threadIdx.x == 0) pp[blockIdx.x] = red[0];
}

__global__ __launch_bounds__(64) void frob_fin(const float* __restrict__ pp,
                                               float* __restrict__ out)
{
    const int b = threadIdx.x;
    float s = 0.f;
#pragma unroll
    for (int i = 0; i < 8; ++i) s += pp[b * 8 + i];
    out[b] = sqrtf(s);
}

// ---------------------------------------------------------------------------
// Y0 = f16(A / norm[b])
// ---------------------------------------------------------------------------
__global__ __launch_bounds__(256) void init_s(const unsigned short* __restrict__ A,
                                              unsigned short* __restrict__ Y,
                                              const float* __restrict__ norm)
{
    const int total = 64 * 32768;
    for (int g = blockIdx.x * 256 + threadIdx.x; g < total; g += gridDim.x * 256) {
        const int b = g >> 15;
        const int off = (g & 32767) * 8;
        const float rn = 1.0f / norm[b];
        ushort8v h = *(const ushort8v*)(A + (size_t)b * SLOT_S + off);
        ushort8v o;
#pragma unroll
        for (int j = 0; j < 8; ++j) o[j] = f2h(h2f(h[j]) * rn);
        *(ushort8v*)(Y + (size_t)b * SLOT_S + off) = o;
    }
}

// ---------------------------------------------------------------------------
// v = f16(sgn_sqrt(y * sqrt(norm[b])))
// ---------------------------------------------------------------------------
__global__ __launch_bounds__(256) void ssqrt_s(const unsigned short* __restrict__ Yf,
                                               unsigned short* __restrict__ Vp,
                                               const float* __restrict__ norm)
{
    const int total = 64 * 32768;
    for (int g = blockIdx.x * 256 + threadIdx.x; g < total; g += gridDim.x * 256) {
        const int b = g >> 15;
        const int off = (g & 32767) * 8;
        const float s = sqrtf(norm[b]);
        ushort8v h = *(const ushort8v*)(Yf + (size_t)b * SLOT_S + off);
        ushort8v o;
#pragma unroll
        for (int j = 0; j < 8; ++j) o[j] = f2h(sgn_sqrt(h2f(h[j]) * s));
        *(ushort8v*)(Vp + (size_t)b * SLOT_S + off) = o;
    }
}

// ---------------------------------------------------------------------------
// FC via MFMA (fp16), k-split: grid 256 (128 sp x 2 nt).
// A = V fp16 (64 rows); B = W fp32 -> fp16 RNE in staging. fp32 partials.
// LDS: A 64x32 @0, B 128x32 @2048; XOR-chunk involution.
// ---------------------------------------------------------------------------
__global__ __launch_bounds__(256) void fc_mfma_s(
    const unsigned short* __restrict__ Vp, const float* __restrict__ Wfc,
    float* __restrict__ part)
{
    __shared__ __align__(16) unsigned short sm2[6144];

    const int sp = blockIdx.x >> 1;
    const int nt = blockIdx.x & 1;
    const int kbase = sp * 2048;
    const int n0 = nt * 128;

    const int t = threadIdx.x;
    const int l = t & 63;
    const int w = t >> 6;
    const int wr = w >> 1, wc = w & 1;
    const int lr = l & 15;
    const int sc = (((l >> 4) ^ ((l >> 1) & 3)) << 3);

    const int sr = t >> 1, sh = t & 1;
    const int swz = (sr >> 1) & 3;
    const int slot0 = ((((sh << 1) | 0) ^ swz) << 3);
    const int slot1 = ((((sh << 1) | 1) ^ swz) << 3);

    const unsigned short* gA = Vp + (size_t)sr * SLOT_S + kbase + sh * 16;   // t<128
    const int wrow = n0 + sr;
    const bool wv = wrow < 200;
    const float* gB = Wfc + (size_t)wrow * 262144 + kbase + sh * 16;

    f32x4 acc[2][4] = {};

    ushort8v va0, va1, vb0, vb1;
    float4 wf0, wf1, wf2, wf3;
#define FLOAD(OFF) do { \
    if (t < 128) { \
        va0 = *(const ushort8v*)(gA + (OFF)); va1 = *(const ushort8v*)(gA + (OFF) + 8); \
    } \
    if (wv) { \
        wf0 = *(const float4*)(gB + (OFF));      wf1 = *(const float4*)(gB + (OFF) + 4); \
        wf2 = *(const float4*)(gB + (OFF) + 8);  wf3 = *(const float4*)(gB + (OFF) + 12); \
    } else { \
        wf0 = wf1 = wf2 = wf3 = make_float4(0.f, 0.f, 0.f, 0.f); \
    } \
    vb0[0] = f2h(wf0.x); vb0[1] = f2h(wf0.y); vb0[2] = f2h(wf0.z); vb0[3] = f2h(wf0.w); \
    vb0[4] = f2h(wf1.x); vb0[5] = f2h(wf1.y); vb0[6] = f2h(wf1.z); vb0[7] = f2h(wf1.w); \
    vb1[0] = f2h(wf2.x); vb1[1] = f2h(wf2.y); vb1[2] = f2h(wf2.z); vb1[3] = f2h(wf2.w); \
    vb1[4] = f2h(wf3.x); vb1[5] = f2h(wf3.y); vb1[6] = f2h(wf3.z); vb1[7] = f2h(wf3.w); \
  } while (0)

    FLOAD(0);
    for (int s = 0; s < 64; ++s) {
        __syncthreads();
        if (t < 128) {
            *(ushort8v*)&sm2[(sr << 5) + slot0] = va0;
            *(ushort8v*)&sm2[(sr << 5) + slot1] = va1;
        }
        *(ushort8v*)&sm2[2048 + (sr << 5) + slot0] = vb0;
        *(ushort8v*)&sm2[2048 + (sr << 5) + slot1] = vb1;
        __syncthreads();
        if (s + 1 < 64) FLOAD((s + 1) * 32);

        half8v ah[2], bh[4];
#pragma unroll
        for (int f = 0; f < 2; ++f) {
            const int ra = ((wr * 32 + f * 16 + lr) << 5) + sc;
            ah[f] = *(const half8v*)(&sm2[ra]);
        }
#pragma unroll
        for (int f = 0; f < 4; ++f) {
            const int rb = ((wc * 64 + f * 16 + lr) << 5) + sc;
            bh[f] = *(const half8v*)(&sm2[2048 + rb]);
        }
#pragma unroll
        for (int fm = 0; fm < 2; ++fm)
#pragma unroll
            for (int fn = 0; fn < 4; ++fn)
                acc[fm][fn] = __builtin_amdgcn_mfma_f32_16x16x32_f16(ah[fm], bh[fn], acc[fm][fn], 0, 0, 0);
    }
#undef FLOAD

    float* pb = part + (size_t)(sp * 2 + nt) * 64 * 128;
#pragma unroll
    for (int fm = 0; fm < 2; ++fm)
#pragma unroll
        for (int j = 0; j < 4; ++j) {
            const int row = wr * 32 + fm * 16 + (l >> 4) * 4 + j;
#pragma unroll
            for (int fn = 0; fn < 4; ++fn) {
                const int col = wc * 64 + fn * 16 + lr;
                pb[(size_t)row * 128 + col] = acc[fm][fn][j];
            }
        }
}

__global__ __launch_bounds__(256) void fc_reduce(
    const float* __restrict__ part, const float* __restrict__ n2,
    const float* __restrict__ bias, float* __restrict__ out)
{
    const int p = blockIdx.x * 256 + threadIdx.x;
    if (p >= 64 * 200) return;
    const int b = p / 200, o = p % 200;
    const int nt = o >> 7, n = o & 127;
    float s = 0.f;
    for (int c = 0; c < 128; ++c)
        s += part[((size_t)(c * 2 + nt) * 64 + b) * 128 + n];
    const float nb = fmaxf(n2[b], 1e-12f);
    out[p] = s / nb + bias[o];
}

// ---------------------------------------------------------------------------
extern "C" void kernel_launch(void* const* d_in, const int* in_sizes, int n_in,
                              void* d_out, int out_size, void* d_ws, size_t ws_size,
                              hipStream_t stream)
{
    const float* X    = (const float*)d_in[0];
    const float* Wfc  = (const float*)d_in[1];
    const float* bias = (const float*)d_in[2];
    float* out = (float*)d_out;

    float* norm  = (float*)d_ws;
    float* norm2 = norm + 64;
    float* fpart = norm2 + 64;                              // 512
    float* part  = fpart + 512;                             // 8 MiB
    unsigned short* region = (unsigned short*)(part + (size_t)256 * 64 * 128);

    unsigned short* P[4];
    for (int i = 0; i < 4; ++i) P[i] = region + (size_t)i * 64 * SLOT_S;

    // A = X X^T / 784 -> P0 (fp16); norm; Y0 = A/norm -> P1
    gram_single<<<640, 256, 0, stream>>>(X, P[0], 1.0f / 784.0f, 800);
    frob_s<<<512, 256, 0, stream>>>(P[0], fpart);
    frob_fin<<<1, 64, 0, stream>>>(fpart, norm);
    init_s<<<1024, 256, 0, stream>>>(P[0], P[1], norm);

    // Newton-Schulz in M-form: T(M) = (3I - M)/2 folded into epilogue
    // it0: Y1 = Y0*T(Y0) -> P2 ; M1 = Y1*T(Y0) -> P3
    ns_single<<<640, 256, 0, stream>>>(P[1], P[1], P[1], P[2], P[2],
        512, (long)SLOT_S, 512, (long)SLOT_S, 512, 1);
    ns_single<<<640, 256, 0, stream>>>(P[2], P[2], P[1], P[3], P[3],
        512, (long)SLOT_S, 512, (long)SLOT_S, 512, 1);

    unsigned short *Y = P[2], *M = P[3], *F0 = P[0], *F1 = P[1];
    for (int it = 1; it <= 8; ++it) {
        // s1 merged: z=0: U = M*T(M) -> F0 ; z=1: Ynew = Y*T(M) -> F1
        ns_single<<<1280, 256, 0, stream>>>(M, Y, M, F0, F1,
            512, (long)SLOT_S, 512, (long)SLOT_S, 512, 2);
        // s2: Mnew = U*T(M) -> old Y slot
        ns_single<<<640, 256, 0, stream>>>(F0, F0, M, Y, Y,
            512, (long)SLOT_S, 512, (long)SLOT_S, 512, 1);
        unsigned short* Mold = M;
        M = Y;        // Mnew lives in old Y slot
        Y = F1;       // Ynew
        F1 = Mold;    // Mold freed
    }
    // it9: YF = Y*T(M) -> F0
    ns_single<<<640, 256, 0, stream>>>(Y, Y, M, F0, F0,
        512, (long)SLOT_S, 512, (long)SLOT_S, 512, 1);

    // v = signed-sqrt, n2 = ||v||, FC head
    unsigned short* Vp = F1;
    ssqrt_s<<<1024, 256, 0, stream>>>(F0, Vp, norm);
    frob_s<<<512, 256, 0, stream>>>(Vp, fpart);
    frob_fin<<<1, 64, 0, stream>>>(fpart, norm2);
    fc_mfma_s<<<dim3(256), 256, 0, stream>>>(Vp, Wfc, part);
    fc_reduce<<<50, 256, 0, stream>>>(part, norm2, bias, out);
}